// Round 1
// baseline (119.075 us; speedup 1.0000x reference)
//
#include <hip/hip_runtime.h>
#include <cfloat>

typedef short bf16x8 __attribute__((ext_vector_type(8)));
typedef float f32x4  __attribute__((ext_vector_type(4)));

#define CHUNK   64
#define NCHUNK  16

static __device__ __forceinline__ short bf16bits(float v) {
    __bf16 h = (__bf16)v;
    return (short)__builtin_bit_cast(unsigned short, h);
}

// ---------------- kernel 1: prep codebook ----------------
__global__ __launch_bounds__(256) void prep_kernel(
    const float* __restrict__ W, unsigned short* __restrict__ wh,
    float* __restrict__ cw, float* __restrict__ lossAcc)
{
    int t   = threadIdx.x;
    int row = blockIdx.x * 16 + (t >> 4);
    int c0  = (t & 15) * 16;
    const float* wr = W + row * 256 + c0;
    float s = 0.f;
    unsigned int packed[8];
#pragma unroll
    for (int i = 0; i < 16; i += 2) {
        float a = wr[i], b = wr[i + 1];
        s += a * a + b * b;
        unsigned short ha = __builtin_bit_cast(unsigned short, (__bf16)a);
        unsigned short hb = __builtin_bit_cast(unsigned short, (__bf16)b);
        packed[i >> 1] = (unsigned int)ha | ((unsigned int)hb << 16);
    }
    uint4* dst = (uint4*)&wh[row * 256 + c0];
    dst[0] = make_uint4(packed[0], packed[1], packed[2], packed[3]);
    dst[1] = make_uint4(packed[4], packed[5], packed[6], packed[7]);
#pragma unroll
    for (int m = 1; m < 16; m <<= 1) s += __shfl_xor(s, m, 64);
    if ((t & 15) == 0) cw[row] = s;
    if (blockIdx.x == 0 && t == 0) *lossAcc = 0.f;
}

// ---------------- kernel 2: fused distance-GEMM + argmin + loss ----------------
// grid 256, block 256 (4 waves). WG = 128 tokens (one batch b, s-range of 128).
// Wave = 32 tokens (2 col-tiles of 16). X hi/lo fragments live in registers.
// W streamed: 16 chunks x 64 codes through 32KB swizzled LDS, reg-prefetched.
__global__ __launch_bounds__(256, 1) void argmin_kernel(
    const float* __restrict__ X, const unsigned short* __restrict__ wh,
    const float* __restrict__ cw, int* __restrict__ gidx,
    float* __restrict__ lossAcc)
{
    __shared__ unsigned short whs[CHUNK * 256];  // 32KB, XOR-swizzled rows
    __shared__ float cwl[1024];

    int tid  = threadIdx.x;
    int lane = tid & 63, wv = tid >> 6;
    int g  = blockIdx.x;
    int b  = g >> 3;
    int s0 = (g & 7) * 128 + wv * 32;            // wave's spatial base within batch b
    const float* xb = X + ((size_t)b << 18);

    for (int i = tid; i < 1024; i += 256) cwl[i] = cw[i];

    int srow = lane & 15;       // token-in-tile / code-in-tile (B col, A row)
    int kgrp = lane >> 4;       // k-group: k = 8*kgrp + i within a K=32 step

    // ---- X fragments (hi/lo bf16) into registers; ||x||^2 on the fly ----
    bf16x8 fxh[2][8], fxl[2][8];
    float tpart[2] = {0.f, 0.f};
#pragma unroll
    for (int tt = 0; tt < 2; ++tt) {
#pragma unroll
        for (int ks = 0; ks < 8; ++ks) {
            bf16x8 h8, l8;
#pragma unroll
            for (int i = 0; i < 8; ++i) {
                int c = ks * 32 + kgrp * 8 + i;
                float v = xb[((size_t)c << 10) + s0 + tt * 16 + srow];
                __bf16 hh = (__bf16)v;
                float  hf = (float)hh;
                h8[i] = (short)__builtin_bit_cast(unsigned short, hh);
                l8[i] = bf16bits(v - hf);
                tpart[tt] = fmaf(v, v, tpart[tt]);
            }
            fxh[tt][ks] = h8; fxl[tt][ks] = l8;
        }
        tpart[tt] += __shfl_xor(tpart[tt], 16, 64);
        tpart[tt] += __shfl_xor(tpart[tt], 32, 64);
    }

    // ---- W staging helpers (256 threads cooperatively stage 64x256 bf16) ----
    int srcRow  = tid >> 2;            // 0..63 code row within chunk
    int srcK    = (tid & 3) * 64;      // k base
    int swz     = (srcRow & 7) << 3;   // element-XOR swizzle (16B granules)
    int dstBase = srcRow * 256;

    uint4 stg[8];
#pragma unroll
    for (int j = 0; j < 8; ++j)
        stg[j] = *(const uint4*)&wh[(size_t)srcRow * 256 + srcK + j * 8];
#pragma unroll
    for (int j = 0; j < 8; ++j)
        *(uint4*)&whs[dstBase + ((srcK + j * 8) ^ swz)] = stg[j];
    __syncthreads();

    float best[2] = {FLT_MAX, FLT_MAX};
    int   bidx[2] = {0, 0};

    for (int ch = 0; ch < NCHUNK; ++ch) {
        if (ch + 1 < NCHUNK) {  // prefetch next chunk into registers
            const unsigned short* src = wh + (size_t)(ch + 1) * CHUNK * 256;
#pragma unroll
            for (int j = 0; j < 8; ++j)
                stg[j] = *(const uint4*)&src[(size_t)srcRow * 256 + srcK + j * 8];
        }

        f32x4 acc[4][2];
#pragma unroll
        for (int rt = 0; rt < 4; ++rt)
#pragma unroll
            for (int tt = 0; tt < 2; ++tt)
                acc[rt][tt] = (f32x4){0.f, 0.f, 0.f, 0.f};

#pragma unroll
        for (int ks = 0; ks < 8; ++ks) {
            bf16x8 af[4];
#pragma unroll
            for (int rt = 0; rt < 4; ++rt) {
                int r = rt * 16 + srow;
                af[rt] = *(const bf16x8*)&whs[r * 256 + ((ks * 32 + kgrp * 8) ^ ((r & 7) << 3))];
            }
#pragma unroll
            for (int rt = 0; rt < 4; ++rt)
#pragma unroll
                for (int tt = 0; tt < 2; ++tt)
                    acc[rt][tt] = __builtin_amdgcn_mfma_f32_16x16x32_bf16(
                        af[rt], fxh[tt][ks], acc[rt][tt], 0, 0, 0);
#pragma unroll
            for (int rt = 0; rt < 4; ++rt)
#pragma unroll
                for (int tt = 0; tt < 2; ++tt)
                    acc[rt][tt] = __builtin_amdgcn_mfma_f32_16x16x32_bf16(
                        af[rt], fxl[tt][ks], acc[rt][tt], 0, 0, 0);
        }

        int cb = ch * CHUNK;
#pragma unroll
        for (int rt = 0; rt < 4; ++rt) {
#pragma unroll
            for (int j = 0; j < 4; ++j) {
                int cl = rt * 16 + kgrp * 4 + j;     // D row = code-in-chunk
                float cwv = cwl[cb + cl];
#pragma unroll
                for (int tt = 0; tt < 2; ++tt) {
                    float e = fmaf(-2.f, acc[rt][tt][j], cwv);
                    bool better = e < best[tt];      // strict < : first index wins
                    best[tt] = better ? e : best[tt];
                    bidx[tt] = better ? (cb + cl) : bidx[tt];
                }
            }
        }
        __syncthreads();
        if (ch + 1 < NCHUNK) {
#pragma unroll
            for (int j = 0; j < 8; ++j)
                *(uint4*)&whs[dstBase + ((srcK + j * 8) ^ swz)] = stg[j];
        }
        __syncthreads();
    }

    // ---- cross-lane argmin reduce (codes split across kgrp groups) ----
    float lossl = 0.f;
    int n0 = g * 128 + wv * 32;
#pragma unroll
    for (int tt = 0; tt < 2; ++tt) {
        float v = best[tt]; int id = bidx[tt];
#pragma unroll
        for (int m = 16; m <= 32; m <<= 1) {
            float ve = __shfl_xor(v, m, 64);
            int   ie = __shfl_xor(id, m, 64);
            if (ve < v || (ve == v && ie < id)) { v = ve; id = ie; }
        }
        if (lane < 16) {
            gidx[n0 + tt * 16 + lane] = id;
            lossl += tpart[tt] + v;   // d_min = ||x||^2 + (cw - 2 x.w)
        }
    }
#pragma unroll
    for (int m = 1; m < 16; m <<= 1) lossl += __shfl_xor(lossl, m, 64);
    if (lane == 0) atomicAdd(lossAcc, lossl);
}

// ---------------- kernel 3: gather + NCHW transpose store + losses ----------------
__global__ __launch_bounds__(256) void out_kernel(
    const float* __restrict__ W, const int* __restrict__ gidx,
    const float* __restrict__ lossAcc, float* __restrict__ out)
{
    __shared__ float tile[256][65];
    __shared__ int lidx[64];
    int t = threadIdx.x, g = blockIdx.x;
    int n0 = g * 64;
    int b = n0 >> 10, sb = n0 & 1023;
    if (t < 64) lidx[t] = gidx[n0 + t];
    __syncthreads();
    int tok = t >> 2, cq = t & 3;
    const float* wr = W + ((size_t)lidx[tok] << 8);
#pragma unroll
    for (int j = 0; j < 16; ++j) {
        int c = cq * 4 + j * 16;
        float4 v = *(const float4*)&wr[c];
        tile[c + 0][tok] = v.x; tile[c + 1][tok] = v.y;
        tile[c + 2][tok] = v.z; tile[c + 3][tok] = v.w;
    }
    __syncthreads();
    float* op = out + (((size_t)(b * 256 + t)) << 10) + sb;
#pragma unroll
    for (int j = 0; j < 16; ++j) {
        float4 v;
        v.x = tile[t][j * 4 + 0]; v.y = tile[t][j * 4 + 1];
        v.z = tile[t][j * 4 + 2]; v.w = tile[t][j * 4 + 3];
        *(float4*)&op[j * 4] = v;
    }
    if (g == 0 && t == 0) {
        float mse = *lossAcc * (1.0f / 8388608.0f);
        out[8388608] = 1.25f * mse;   // vq_loss = 0.25*mse + mse
        out[8388609] = mse;           // embedding_loss
        out[8388610] = mse;           // commitment_loss
    }
}

extern "C" void kernel_launch(void* const* d_in, const int* in_sizes, int n_in,
                              void* d_out, int out_size, void* d_ws, size_t ws_size,
                              hipStream_t stream)
{
    (void)in_sizes; (void)n_in; (void)out_size; (void)ws_size;
    const float* X = (const float*)d_in[0];   // [32,256,32,32] fp32
    const float* W = (const float*)d_in[1];   // [1024,256] fp32
    float* out = (float*)d_out;               // [8388608 out | vq | emb | commit]
    char* ws = (char*)d_ws;
    float*          lossAcc = (float*)ws;                          // 4B
    float*          cw      = (float*)(ws + 256);                  // 4KB
    unsigned short* wh      = (unsigned short*)(ws + 256 + 4096);  // 512KB bf16
    int*            gidx    = (int*)(ws + 256 + 4096 + 524288);    // 128KB

    prep_kernel<<<64, 256, 0, stream>>>(W, wh, cw, lossAcc);
    argmin_kernel<<<256, 256, 0, stream>>>(X, wh, cw, gidx, lossAcc);
    out_kernel<<<512, 256, 0, stream>>>(W, gidx, lossAcc, out);
}

// Round 2
// 54.168 us; speedup vs baseline: 2.1983x; 2.1983x over previous
//
#include <hip/hip_runtime.h>
#include <cfloat>

typedef short bf16x8 __attribute__((ext_vector_type(8)));
typedef float f32x4  __attribute__((ext_vector_type(4)));

#define NCH 16      // chunks per quarter (256 codes / 16)

static __device__ __forceinline__ void gl_lds16(const void* g, void* l) {
    __builtin_amdgcn_global_load_lds(
        (const __attribute__((address_space(1))) unsigned int*)g,
        (__attribute__((address_space(3))) unsigned int*)l, 16, 0, 0);
}

// ---------------- kernel 1: prep codebook (bf16 cast + ||w||^2 + zero loss) ----
__global__ __launch_bounds__(256) void prep_kernel(
    const float* __restrict__ W, unsigned short* __restrict__ wh,
    float* __restrict__ cw, float* __restrict__ lossAcc)
{
    int t   = threadIdx.x;
    int row = blockIdx.x * 16 + (t >> 4);
    int c0  = (t & 15) * 16;
    const float* wr = W + row * 256 + c0;
    float s = 0.f;
    unsigned int packed[8];
#pragma unroll
    for (int i = 0; i < 16; i += 2) {
        float a = wr[i], b = wr[i + 1];
        s += a * a + b * b;
        unsigned short ha = __builtin_bit_cast(unsigned short, (__bf16)a);
        unsigned short hb = __builtin_bit_cast(unsigned short, (__bf16)b);
        packed[i >> 1] = (unsigned int)ha | ((unsigned int)hb << 16);
    }
    uint4* dst = (uint4*)&wh[row * 256 + c0];
    dst[0] = make_uint4(packed[0], packed[1], packed[2], packed[3]);
    dst[1] = make_uint4(packed[4], packed[5], packed[6], packed[7]);
#pragma unroll
    for (int m = 1; m < 16; m <<= 1) s += __shfl_xor(s, m, 64);
    if ((t & 15) == 0) cw[row] = s;
    if (blockIdx.x == 0 && t == 0) *lossAcc = 0.f;
}

// ---------------- kernel 2: fused distance-GEMM + argmin + loss ----------------
// grid 512 x 256thr (2 blocks/CU). Block = 64 tokens. Wave q owns ALL 64 tokens
// (4 col-tiles of 16) x codes [q*256, q*256+256): private LDS stream, double-
// buffered 16-code chunks via global_load_lds (pre-swizzled source), NO barriers
// in the main loop. Cross-wave (code-quarter) argmin combine at the end.
__global__ __launch_bounds__(256, 2) void argmin_kernel(
    const float* __restrict__ X, const unsigned short* __restrict__ wh,
    const float* __restrict__ cw, int* __restrict__ gidx,
    float* __restrict__ lossAcc)
{
    __shared__ unsigned short whs[2][4][16 * 256];   // 64KB: [buf][quarter][row*256+e]

    int tid  = threadIdx.x;
    int lane = tid & 63;
    int q    = tid >> 6;              // wave index = code quarter
    int srow = lane & 15;             // token-in-tile (B col) / code row (A row)
    int kgrp = lane >> 4;             // k-group within K=32 MFMA step
    int b    = blockIdx.x;
    int batch = b >> 4;
    int sbase = (b & 15) * 64;
    const float* xb = X + ((size_t)batch << 18) + sbase;

    const char* whb = (const char*)wh;
    int rl0 = lane >> 5;              // row parity within a 1KB DMA call
    int gcol = lane & 31;             // 16B granule within a 512B row

    // stage quarter-q chunk ch into whs[buf][q]: 16 rows x 512B, swizzled source
    auto stage = [&](int ch, int buf) {
        char* ldsbase = (char*)&whs[buf][q][0];
        int codeBase = q * 256 + ch * 16;
#pragma unroll
        for (int c = 0; c < 8; ++c) {
            int r  = c * 2 + rl0;
            int gs = gcol ^ (r & 7);   // involution: LDS stays linear, source swizzled
            gl_lds16(whb + (size_t)(codeBase + r) * 512 + gs * 16, ldsbase + c * 1024);
        }
    };

    stage(0, 0);   // overlap chunk-0 W stream with the X register load below

    // ---- X fragments (bf16) into registers; ||x||^2 on the fly ----
    bf16x8 fx[4][8];
    float tpart[4] = {0.f, 0.f, 0.f, 0.f};
#pragma unroll
    for (int tt = 0; tt < 4; ++tt) {
#pragma unroll
        for (int ks = 0; ks < 8; ++ks) {
            bf16x8 h;
#pragma unroll
            for (int i = 0; i < 8; ++i) {
                int c = ks * 32 + kgrp * 8 + i;
                float v = xb[((size_t)c << 10) + tt * 16 + srow];
                h[i] = (short)__builtin_bit_cast(unsigned short, (__bf16)v);
                tpart[tt] = fmaf(v, v, tpart[tt]);
            }
            fx[tt][ks] = h;
        }
        tpart[tt] += __shfl_xor(tpart[tt], 16, 64);
        tpart[tt] += __shfl_xor(tpart[tt], 32, 64);
    }

    asm volatile("s_waitcnt vmcnt(0)" ::: "memory");   // chunk 0 landed (own wave)

    float best[4] = {FLT_MAX, FLT_MAX, FLT_MAX, FLT_MAX};
    int   bidx[4] = {0, 0, 0, 0};
    const float* cwq = cw + q * 256;
    int cur = 0;

    for (int ch = 0; ch < NCH; ++ch) {
        if (ch + 1 < NCH) stage(ch + 1, cur ^ 1);      // prefetch overlaps compute
        float4 cw4 = *(const float4*)&cwq[ch * 16 + kgrp * 4];

        const unsigned short* wq = &whs[cur][q][0];
        bf16x8 af[8];
#pragma unroll
        for (int ks = 0; ks < 8; ++ks)
            af[ks] = *(const bf16x8*)&wq[srow * 256 + (((ks * 4 + kgrp) ^ (srow & 7)) * 8)];

        f32x4 acc[4];
#pragma unroll
        for (int tt = 0; tt < 4; ++tt) acc[tt] = (f32x4){0.f, 0.f, 0.f, 0.f};
#pragma unroll
        for (int ks = 0; ks < 8; ++ks)
#pragma unroll
            for (int tt = 0; tt < 4; ++tt)
                acc[tt] = __builtin_amdgcn_mfma_f32_16x16x32_bf16(
                    af[ks], fx[tt][ks], acc[tt], 0, 0, 0);

        int cb = q * 256 + ch * 16 + kgrp * 4;
#pragma unroll
        for (int j = 0; j < 4; ++j) {
            float cwv = j == 0 ? cw4.x : j == 1 ? cw4.y : j == 2 ? cw4.z : cw4.w;
#pragma unroll
            for (int tt = 0; tt < 4; ++tt) {
                float e = fmaf(-2.f, acc[tt][j], cwv);
                bool better = e < best[tt];            // strict <: first (lowest) code wins
                best[tt] = better ? e : best[tt];
                bidx[tt] = better ? (cb + j) : bidx[tt];
            }
        }
        asm volatile("s_waitcnt vmcnt(0)" ::: "memory");  // own prefetch landed
        cur ^= 1;
    }

    // waves drift (no main-loop barriers): sync before overlaying reduce scratch on whs
    __syncthreads();
    float* redv = (float*)&whs[0][0][0];               // 4*64 f32
    int*   redi = (int*)((char*)&whs[0][0][0] + 1024); // 4*64 i32
    float* redt = (float*)((char*)&whs[0][0][0] + 2048); // 64 f32 (||x||^2)

#pragma unroll
    for (int tt = 0; tt < 4; ++tt) {
        float v = best[tt]; int id = bidx[tt];
#pragma unroll
        for (int m = 16; m <= 32; m <<= 1) {
            float ve = __shfl_xor(v, m, 64);
            int   ie = __shfl_xor(id, m, 64);
            if (ve < v || (ve == v && ie < id)) { v = ve; id = ie; }
        }
        if (lane < 16) {
            redv[q * 64 + tt * 16 + lane] = v;
            redi[q * 64 + tt * 16 + lane] = id;
            if (q == 0) redt[tt * 16 + lane] = tpart[tt];
        }
    }
    __syncthreads();

    if (tid < 64) {
        float v = redv[tid]; int id = redi[tid];
#pragma unroll
        for (int qq = 1; qq < 4; ++qq) {
            float vq = redv[qq * 64 + tid];
            if (vq < v) { v = vq; id = redi[qq * 64 + tid]; }  // tie -> lower quarter
        }
        gidx[b * 64 + tid] = id;
        float dl = redt[tid] + v;                      // d_min = ||x||^2 - 2x.w + ||w||^2
#pragma unroll
        for (int m = 1; m < 64; m <<= 1) dl += __shfl_xor(dl, m, 64);
        if (tid == 0) atomicAdd(lossAcc, dl);
    }
}

// ---------------- kernel 3: gather + NCHW transpose store + losses ----------------
__global__ __launch_bounds__(256) void out_kernel(
    const float* __restrict__ W, const int* __restrict__ gidx,
    const float* __restrict__ lossAcc, float* __restrict__ out)
{
    __shared__ float tile[256][65];
    __shared__ int lidx[64];
    int t = threadIdx.x, g = blockIdx.x;
    int n0 = g * 64;
    int b = n0 >> 10, sb = n0 & 1023;
    if (t < 64) lidx[t] = gidx[n0 + t];
    __syncthreads();
    int tok = t >> 2, cq = t & 3;
    const float* wr = W + ((size_t)lidx[tok] << 8);
#pragma unroll
    for (int j = 0; j < 16; ++j) {
        int c = cq * 4 + j * 16;
        float4 v = *(const float4*)&wr[c];
        tile[c + 0][tok] = v.x; tile[c + 1][tok] = v.y;
        tile[c + 2][tok] = v.z; tile[c + 3][tok] = v.w;
    }
    __syncthreads();
    float* op = out + (((size_t)(b * 256 + t)) << 10) + sb;
#pragma unroll
    for (int j = 0; j < 16; ++j) {
        float4 v;
        v.x = tile[t][j * 4 + 0]; v.y = tile[t][j * 4 + 1];
        v.z = tile[t][j * 4 + 2]; v.w = tile[t][j * 4 + 3];
        *(float4*)&op[j * 4] = v;
    }
    if (g == 0 && t == 0) {
        float mse = *lossAcc * (1.0f / 8388608.0f);
        out[8388608] = 1.25f * mse;   // vq_loss
        out[8388609] = mse;           // embedding_loss
        out[8388610] = mse;           // commitment_loss
    }
}

extern "C" void kernel_launch(void* const* d_in, const int* in_sizes, int n_in,
                              void* d_out, int out_size, void* d_ws, size_t ws_size,
                              hipStream_t stream)
{
    (void)in_sizes; (void)n_in; (void)out_size; (void)ws_size;
    const float* X = (const float*)d_in[0];   // [32,256,32,32] fp32
    const float* W = (const float*)d_in[1];   // [1024,256] fp32
    float* out = (float*)d_out;               // [8388608 out | vq | emb | commit]
    char* ws = (char*)d_ws;
    float*          lossAcc = (float*)ws;                          // 4B
    float*          cw      = (float*)(ws + 256);                  // 4KB
    unsigned short* wh      = (unsigned short*)(ws + 256 + 4096);  // 512KB bf16
    int*            gidx    = (int*)(ws + 256 + 4096 + 524288);    // 128KB

    prep_kernel<<<64, 256, 0, stream>>>(W, wh, cw, lossAcc);
    argmin_kernel<<<512, 256, 0, stream>>>(X, wh, cw, gidx, lossAcc);
    out_kernel<<<512, 256, 0, stream>>>(W, gidx, lossAcc, out);
}